// Round 5
// baseline (212.341 us; speedup 1.0000x reference)
//
#include <hip/hip_runtime.h>
#include <stdint.h>

#define Tn 65536
#define Dn 768
#define NSEG 4096   // B*S = 32*128

typedef __bf16 bf16;
typedef __bf16 bf16x8 __attribute__((ext_vector_type(8)));
typedef float f32x4 __attribute__((ext_vector_type(4)));

__device__ inline f32x4 ntload(const f32x4* p) {
  return __builtin_nontemporal_load(p);
}

// ---- Kernel 1 (fused): pool+LN | W fp32->bf16 | padding-mask zeros ---------
// blocks [0,4096): one wave per sentence slot (pool+enrich+LN).
// blocks [4096,6400): convert proj_w to bf16 (2304 blocks x 64 x float4).
// blocks [6400,6416): zero the 4096-float padding mask (float4 stores).
// Pool blocks find their segment bounds via interleaved dual binary search
// (no precomputed starts -> no prior kernel dependency).
__global__ __launch_bounds__(64, 4) void k_fused(
    const int* __restrict__ token_ids, const int* __restrict__ seg,
    const int* __restrict__ section_ids, const int* __restrict__ temporality_ids,
    const int* __restrict__ negation_ids, const int* __restrict__ position_ids,
    const int* __restrict__ timestamp_ids,
    const float* __restrict__ token_table, const float* __restrict__ section_table,
    const float* __restrict__ temporality_table, const float* __restrict__ negation_table,
    const float* __restrict__ position_table, const float* __restrict__ timestamp_table,
    const float* __restrict__ gamma, const float* __restrict__ beta,
    bf16* __restrict__ out_normed,
    const float* __restrict__ w, bf16* __restrict__ wb,
    float* __restrict__ mask_out)
{
  const int b = blockIdx.x;
  const int lane = threadIdx.x;

  if (b >= NSEG) {                       // ---- side work, overlapped with pool
    if (b < NSEG + 2304) {
      const int i = (b - NSEG) * 64 + lane;        // 147456 float4 of W
      const float4 v = ((const float4*)w)[i];
      alignas(8) bf16 o[4] = {(bf16)v.x, (bf16)v.y, (bf16)v.z, (bf16)v.w};
      ((ushort4*)wb)[i] = *(ushort4*)o;
    } else {
      const int i = (b - (NSEG + 2304)) * 64 + lane;  // 1024 float4 of zeros
      ((float4*)mask_out)[i] = make_float4(0.f, 0.f, 0.f, 0.f);
    }
    return;
  }

  const int n = b;
  // interleaved dual binary search: start = lower_bound(n), end = lower_bound(n+1)
  int lo1 = 0, hi1 = Tn, lo2 = 0, hi2 = Tn;
  #pragma unroll 1
  for (int it = 0; it < 16; ++it) {      // 2^16 == Tn: fully converged
    const int m1 = (lo1 + hi1) >> 1;
    const int m2 = (lo2 + hi2) >> 1;
    const int v1 = seg[m1];
    const int v2 = seg[m2];
    if (v1 < n)     lo1 = m1 + 1; else hi1 = m1;
    if (v2 < n + 1) lo2 = m2 + 1; else hi2 = m2;
  }
  const int start = lo1, end = lo2;
  const float scale = 1.0f / fmaxf((float)(end - start), 1.0f);

  const f32x4* tt = (const f32x4*)token_table;   // row stride = 192 f32x4

  // enrichment rows (cached loads; tiny tables, heavy cross-block reuse)
  const f32x4* e1 = (const f32x4*)(section_table     + (size_t)section_ids[n]     * Dn);
  const f32x4* e2 = (const f32x4*)(temporality_table + (size_t)temporality_ids[n] * Dn);
  const f32x4* e3 = (const f32x4*)(negation_table    + (size_t)negation_ids[n]    * Dn);
  const f32x4* e4 = (const f32x4*)(position_table    + (size_t)position_ids[n]    * Dn);
  const f32x4* e5 = (const f32x4*)(timestamp_table   + (size_t)timestamp_ids[n]   * Dn);
  f32x4 en[3];
  #pragma unroll
  for (int j = 0; j < 3; ++j) {
    const int d = j * 64 + lane;
    en[j] = e1[d] + e2[d] + e3[d] + e4[d] + e5[d];
  }

  f32x4 acc[3];
  #pragma unroll
  for (int j = 0; j < 3; ++j) acc[j] = (f32x4){0.f, 0.f, 0.f, 0.f};

  // ids for the first 6-token batch (clamped so prefetch never reads OOB)
  int t = start;
  int ids[6];
  #pragma unroll
  for (int u = 0; u < 6; ++u)
    ids[u] = token_ids[(t + u < Tn) ? t + u : Tn - 1];

  while (t + 6 <= end) {
    f32x4 L[6][3];
    #pragma unroll
    for (int u = 0; u < 6; ++u) {
      const f32x4* r = tt + (size_t)ids[u] * 192;
      #pragma unroll
      for (int j = 0; j < 3; ++j) L[u][j] = ntload(r + j * 64 + lane);
    }
    t += 6;
    #pragma unroll
    for (int u = 0; u < 6; ++u)          // prefetch next ids while loads fly
      ids[u] = token_ids[(t + u < Tn) ? t + u : Tn - 1];
    #pragma unroll
    for (int j = 0; j < 3; ++j) {
      L[0][j] += L[1][j]; L[2][j] += L[3][j]; L[4][j] += L[5][j];
      acc[j] += (L[0][j] + L[2][j]) + L[4][j];
    }
  }
  // tail (<6): branch-uniform guards, loads issued back-to-back
  #pragma unroll
  for (int u = 0; u < 5; ++u) {
    if (t + u < end) {
      const f32x4* r = tt + (size_t)ids[u] * 192;
      #pragma unroll
      for (int j = 0; j < 3; ++j) acc[j] += ntload(r + j * 64 + lane);
    }
  }

  f32x4 e[3];
  #pragma unroll
  for (int j = 0; j < 3; ++j) e[j] = acc[j] * scale + en[j];

  // LayerNorm via wave butterfly
  float s = 0.f;
  #pragma unroll
  for (int j = 0; j < 3; ++j) s += e[j][0] + e[j][1] + e[j][2] + e[j][3];
  #pragma unroll
  for (int o = 32; o > 0; o >>= 1) s += __shfl_xor(s, o, 64);
  const float mu = s * (1.0f / 768.0f);

  float v = 0.f;
  #pragma unroll
  for (int j = 0; j < 3; ++j) {
    e[j] -= mu;
    v += e[j][0]*e[j][0] + e[j][1]*e[j][1] + e[j][2]*e[j][2] + e[j][3]*e[j][3];
  }
  #pragma unroll
  for (int o = 32; o > 0; o >>= 1) v += __shfl_xor(v, o, 64);
  const float inv = rsqrtf(v * (1.0f / 768.0f) + 1e-5f);

  #pragma unroll
  for (int j = 0; j < 3; ++j) {
    const int d = j * 64 + lane;
    const f32x4 g = ((const f32x4*)gamma)[d];
    const f32x4 bb = ((const f32x4*)beta)[d];
    const f32x4 r = e[j] * inv * g + bb;
    alignas(8) bf16 o[4] = {(bf16)r[0], (bf16)r[1], (bf16)r[2], (bf16)r[3]};
    *(ushort4*)(out_normed + (size_t)n * Dn + 4 * d) = *(ushort4*)o;
  }
}

// ------------- Kernel 2: out = normed @ W^T + bias  (bf16 MFMA) -------------
// A: [4096,768] bf16 row-major.  W: [768,768] bf16 row-major ([e][d] = [N][K]).
// BM=64, BN=128, BK=32 -> grid 6x64 = 384 blocks.
__global__ __launch_bounds__(256) void k_gemm(
    const bf16* __restrict__ A, const bf16* __restrict__ W,
    const float* __restrict__ bias, float* __restrict__ out)
{
  __shared__ bf16 As[64 * 32];    // 4 KB
  __shared__ bf16 Bs[128 * 32];   // 8 KB
  const int tid  = threadIdx.x;
  const int lane = tid & 63;
  const int w    = tid >> 6;
  const int m0 = blockIdx.y * 64;
  const int n0 = blockIdx.x * 128;
  const int wm = (w >> 1) * 32;
  const int wn = (w & 1) * 64;

  f32x4 acc[2][4];
  #pragma unroll
  for (int i = 0; i < 2; ++i)
    #pragma unroll
    for (int j = 0; j < 4; ++j) acc[i][j] = (f32x4){0.f, 0.f, 0.f, 0.f};

  const int fr = tid >> 2;
  const int fc = (tid & 3) * 8;
  const bf16* agp = A + (size_t)(m0 + fr) * 768 + fc;
  const bf16* bgp = W + (size_t)(n0 + fr) * 768 + fc;

  for (int kt = 0; kt < 24; ++kt) {
    __syncthreads();
    __builtin_amdgcn_global_load_lds(
        (const __attribute__((address_space(1))) void*)(agp + kt * 32),
        (__attribute__((address_space(3))) void*)(As + tid * 8), 16, 0, 0);
    #pragma unroll
    for (int it = 0; it < 2; ++it) {
      const int f = it * 256 + tid;
      __builtin_amdgcn_global_load_lds(
          (const __attribute__((address_space(1))) void*)(bgp + (size_t)it * 64 * 768 + kt * 32),
          (__attribute__((address_space(3))) void*)(Bs + f * 8), 16, 0, 0);
    }
    __syncthreads();

    bf16x8 af[2], bfr[4];
    #pragma unroll
    for (int i = 0; i < 2; ++i)
      af[i] = *(const bf16x8*)(As + (wm + i * 16 + (lane & 15)) * 32 + (lane >> 4) * 8);
    #pragma unroll
    for (int j = 0; j < 4; ++j)
      bfr[j] = *(const bf16x8*)(Bs + (wn + j * 16 + (lane & 15)) * 32 + (lane >> 4) * 8);

    #pragma unroll
    for (int i = 0; i < 2; ++i)
      #pragma unroll
      for (int j = 0; j < 4; ++j)
        acc[i][j] = __builtin_amdgcn_mfma_f32_16x16x32_bf16(af[i], bfr[j], acc[i][j], 0, 0, 0);
  }

  float bvals[4];
  #pragma unroll
  for (int j = 0; j < 4; ++j) bvals[j] = bias[n0 + wn + j * 16 + (lane & 15)];
  const int r0 = (lane >> 4) * 4;
  #pragma unroll
  for (int i = 0; i < 2; ++i) {
    #pragma unroll
    for (int r = 0; r < 4; ++r) {
      const int gm = m0 + wm + i * 16 + r0 + r;
      float* orow = out + (size_t)gm * 768 + n0 + wn;
      #pragma unroll
      for (int j = 0; j < 4; ++j)
        orow[j * 16 + (lane & 15)] = acc[i][j][r] + bvals[j];
    }
  }
}

extern "C" void kernel_launch(void* const* d_in, const int* in_sizes, int n_in,
                              void* d_out, int out_size, void* d_ws, size_t ws_size,
                              hipStream_t stream) {
  const int* token_ids       = (const int*)d_in[0];
  const int* segment_ids     = (const int*)d_in[1];
  const int* section_ids     = (const int*)d_in[2];
  const int* temporality_ids = (const int*)d_in[3];
  const int* negation_ids    = (const int*)d_in[4];
  const int* position_ids    = (const int*)d_in[5];
  const int* timestamp_ids   = (const int*)d_in[6];
  const float* token_table       = (const float*)d_in[7];
  const float* section_table     = (const float*)d_in[8];
  const float* temporality_table = (const float*)d_in[9];
  const float* negation_table    = (const float*)d_in[10];
  const float* position_table    = (const float*)d_in[11];
  const float* timestamp_table   = (const float*)d_in[12];
  const float* ln_gamma = (const float*)d_in[13];
  const float* ln_beta  = (const float*)d_in[14];
  const float* proj_w   = (const float*)d_in[15];
  const float* proj_b   = (const float*)d_in[16];

  float* out = (float*)d_out;
  bf16* wsW = (bf16*)d_ws;                        // 768*768 bf16   (1.18 MB)
  bf16* wsN = wsW + (size_t)Dn * Dn;              // 4096*768 bf16  (6.29 MB)

  // fused: pool+LN (4096) | W convert (2304) | mask zeros (16)
  k_fused<<<NSEG + 2304 + 16, 64, 0, stream>>>(token_ids, segment_ids,
      section_ids, temporality_ids, negation_ids, position_ids, timestamp_ids,
      token_table, section_table, temporality_table, negation_table,
      position_table, timestamp_table, ln_gamma, ln_beta, wsN,
      proj_w, wsW, out + (size_t)NSEG * Dn);
  // projection GEMM + bias
  k_gemm<<<dim3(6, 64), 256, 0, stream>>>(wsN, wsW, proj_b, out);
}

// Round 6
// 204.812 us; speedup vs baseline: 1.0368x; 1.0368x over previous
//
#include <hip/hip_runtime.h>
#include <stdint.h>

#define Tn 65536
#define Dn 768
#define NSEG 4096   // B*S = 32*128

typedef __bf16 bf16;
typedef __bf16 bf16x8 __attribute__((ext_vector_type(8)));
typedef float f32x4 __attribute__((ext_vector_type(4)));

__device__ inline void f4add(float4& a, const float4& v) {
  a.x += v.x; a.y += v.y; a.z += v.z; a.w += v.w;
}

// ---- Kernel 1: proj_w fp32->bf16  +  padding-mask zeros  +  segment bounds -
// blocks [0,576): convert W; [576,592): zero mask; [592,848): segment starts.
__global__ __launch_bounds__(256) void k_prep(
    const float* __restrict__ w, bf16* __restrict__ wb,
    float* __restrict__ mask_out,
    const int* __restrict__ seg, int* __restrict__ starts)
{
  const int b = blockIdx.x;
  if (b < 576) {
    const int i = b * 256 + threadIdx.x;   // 147456 threads, 4 elems each
    const float4 v = ((const float4*)w)[i];
    alignas(8) bf16 o[4] = {(bf16)v.x, (bf16)v.y, (bf16)v.z, (bf16)v.w};
    ((ushort4*)wb)[i] = *(ushort4*)o;
  } else if (b < 592) {
    mask_out[(b - 576) * 256 + threadIdx.x] = 0.0f;   // 16x256 = 4096
  } else {
    const int t = (b - 592) * 256 + threadIdx.x;      // 0..65535
    const int s = seg[t];
    const int sp = (t == 0) ? -1 : seg[t - 1];
    for (int k = sp + 1; k <= s; ++k) starts[k] = t;  // first idx with seg>=k
    if (t == Tn - 1)
      for (int k = s + 1; k <= NSEG; ++k) starts[k] = Tn;
  }
}

// ---------------- Kernel 2: ragged mean-pool + enrich + LayerNorm -> bf16 ---
// One wave per sentence slot; lane owns 3 float4 (12 dims). No __syncthreads.
// 8-token batches: 24 outstanding 16B loads/lane; next batch's ids prefetched
// (wave-uniform -> SGPRs) before the accumulate tree consumes the loads.
__global__ void k_pool_ln(
    const int* __restrict__ token_ids, const int* __restrict__ starts,
    const int* __restrict__ section_ids, const int* __restrict__ temporality_ids,
    const int* __restrict__ negation_ids, const int* __restrict__ position_ids,
    const int* __restrict__ timestamp_ids,
    const float* __restrict__ token_table, const float* __restrict__ section_table,
    const float* __restrict__ temporality_table, const float* __restrict__ negation_table,
    const float* __restrict__ position_table, const float* __restrict__ timestamp_table,
    const float* __restrict__ gamma, const float* __restrict__ beta,
    bf16* __restrict__ out_normed)
{
  const int n = blockIdx.x;
  const int lane = threadIdx.x;
  const int start = starts[n];
  const int end   = starts[n + 1];
  const float scale = 1.0f / fmaxf((float)(end - start), 1.0f);

  const float4* tt = (const float4*)token_table;   // row stride = 192 float4

  // enrichment rows (issued early; ids are wave-uniform scalar loads)
  const float4* e1 = (const float4*)(section_table     + (size_t)section_ids[n]     * Dn);
  const float4* e2 = (const float4*)(temporality_table + (size_t)temporality_ids[n] * Dn);
  const float4* e3 = (const float4*)(negation_table    + (size_t)negation_ids[n]    * Dn);
  const float4* e4 = (const float4*)(position_table    + (size_t)position_ids[n]    * Dn);
  const float4* e5 = (const float4*)(timestamp_table   + (size_t)timestamp_ids[n]   * Dn);
  float4 en[3];
  #pragma unroll
  for (int j = 0; j < 3; ++j) {
    const int d = j * 64 + lane;
    float4 q = e1[d];
    f4add(q, e2[d]); f4add(q, e3[d]); f4add(q, e4[d]); f4add(q, e5[d]);
    en[j] = q;
  }

  float4 acc[3];
  #pragma unroll
  for (int j = 0; j < 3; ++j) acc[j] = make_float4(0.f, 0.f, 0.f, 0.f);

  // ids for the first batch (clamped so prefetch never reads OOB)
  int t = start;
  int ids[8];
  #pragma unroll
  for (int u = 0; u < 8; ++u)
    ids[u] = token_ids[(t + u < Tn) ? t + u : Tn - 1];

  while (t + 8 <= end) {
    float4 L[8][3];
    #pragma unroll
    for (int u = 0; u < 8; ++u) {
      const float4* r = tt + (size_t)ids[u] * 192;
      #pragma unroll
      for (int j = 0; j < 3; ++j) L[u][j] = r[j * 64 + lane];
    }
    t += 8;
    // prefetch next batch's ids while the 24 loads are in flight
    #pragma unroll
    for (int u = 0; u < 8; ++u)
      ids[u] = token_ids[(t + u < Tn) ? t + u : Tn - 1];
    #pragma unroll
    for (int j = 0; j < 3; ++j) {
      f4add(L[0][j], L[1][j]); f4add(L[2][j], L[3][j]);
      f4add(L[4][j], L[5][j]); f4add(L[6][j], L[7][j]);
      f4add(L[0][j], L[2][j]); f4add(L[4][j], L[6][j]);
      f4add(L[0][j], L[4][j]); f4add(acc[j], L[0][j]);
    }
  }
  // tail (<8 tokens): ids[] already holds ids for t..t+7
  for (int u = 0; t < end; ++t, ++u) {
    const float4* r = tt + (size_t)ids[u] * 192;
    #pragma unroll
    for (int j = 0; j < 3; ++j) f4add(acc[j], r[j * 64 + lane]);
  }

  float4 e[3];
  #pragma unroll
  for (int j = 0; j < 3; ++j) {
    e[j].x = acc[j].x * scale + en[j].x;
    e[j].y = acc[j].y * scale + en[j].y;
    e[j].z = acc[j].z * scale + en[j].z;
    e[j].w = acc[j].w * scale + en[j].w;
  }

  // LayerNorm via wave butterfly (all lanes end with the total)
  float s = 0.f;
  #pragma unroll
  for (int j = 0; j < 3; ++j) s += e[j].x + e[j].y + e[j].z + e[j].w;
  #pragma unroll
  for (int o = 32; o > 0; o >>= 1) s += __shfl_xor(s, o, 64);
  const float mu = s * (1.0f / 768.0f);

  float v = 0.f;
  #pragma unroll
  for (int j = 0; j < 3; ++j) {
    e[j].x -= mu; e[j].y -= mu; e[j].z -= mu; e[j].w -= mu;
    v += e[j].x * e[j].x + e[j].y * e[j].y + e[j].z * e[j].z + e[j].w * e[j].w;
  }
  #pragma unroll
  for (int o = 32; o > 0; o >>= 1) v += __shfl_xor(v, o, 64);
  const float inv = rsqrtf(v * (1.0f / 768.0f) + 1e-5f);

  #pragma unroll
  for (int j = 0; j < 3; ++j) {
    const int d = j * 64 + lane;
    const float4 g = ((const float4*)gamma)[d];
    const float4 b = ((const float4*)beta)[d];
    alignas(8) bf16 o[4];
    o[0] = (bf16)(e[j].x * inv * g.x + b.x);
    o[1] = (bf16)(e[j].y * inv * g.y + b.y);
    o[2] = (bf16)(e[j].z * inv * g.z + b.z);
    o[3] = (bf16)(e[j].w * inv * g.w + b.w);
    *(ushort4*)(out_normed + (size_t)n * Dn + 4 * d) = *(ushort4*)o;
  }
}

// ------------- Kernel 3: out = normed @ W^T + bias  (bf16 MFMA) -------------
// A: [4096,768] bf16 row-major.  W: [768,768] bf16 row-major ([e][d] = [N][K]).
// BM=32, BN=128, BK=32 -> grid 6x128 = 768 blocks = exactly 3/CU (no tail).
// 4 waves; wave w computes the 32x32 subtile at cols w*32 (acc[2][2]).
__global__ __launch_bounds__(256) void k_gemm(
    const bf16* __restrict__ A, const bf16* __restrict__ W,
    const float* __restrict__ bias, float* __restrict__ out)
{
  __shared__ bf16 As[32 * 32];    // 2 KB
  __shared__ bf16 Bs[128 * 32];   // 8 KB
  const int tid  = threadIdx.x;
  const int lane = tid & 63;
  const int w    = tid >> 6;
  const int m0 = blockIdx.y * 32;
  const int n0 = blockIdx.x * 128;
  const int wn = w * 32;

  f32x4 acc[2][2];
  #pragma unroll
  for (int i = 0; i < 2; ++i)
    #pragma unroll
    for (int j = 0; j < 2; ++j) acc[i][j] = (f32x4){0.f, 0.f, 0.f, 0.f};

  // staging: thread t covers row t>>2, cols ((t&3)*8..+7)  (16 B per thread)
  const int fr = tid >> 2;
  const int fc = (tid & 3) * 8;
  const bf16* agp = A + (size_t)(m0 + fr) * 768 + fc;   // rows 0..63 used for t<128
  const bf16* bgp = W + (size_t)(n0 + fr) * 768 + fc;

  for (int kt = 0; kt < 24; ++kt) {
    __syncthreads();
    if (tid < 128)            // As: 32 rows x 32 cols = 2 KB = 128 x 16 B
      __builtin_amdgcn_global_load_lds(
          (const __attribute__((address_space(1))) void*)(agp + kt * 32),
          (__attribute__((address_space(3))) void*)(As + tid * 8), 16, 0, 0);
    #pragma unroll
    for (int it = 0; it < 2; ++it) {   // Bs: 128 rows x 32 cols = 8 KB
      const int f = it * 256 + tid;
      __builtin_amdgcn_global_load_lds(
          (const __attribute__((address_space(1))) void*)(bgp + (size_t)it * 64 * 768 + kt * 32),
          (__attribute__((address_space(3))) void*)(Bs + f * 8), 16, 0, 0);
    }
    __syncthreads();

    bf16x8 af[2], bfr[2];
    #pragma unroll
    for (int i = 0; i < 2; ++i)
      af[i] = *(const bf16x8*)(As + (i * 16 + (lane & 15)) * 32 + (lane >> 4) * 8);
    #pragma unroll
    for (int j = 0; j < 2; ++j)
      bfr[j] = *(const bf16x8*)(Bs + (wn + j * 16 + (lane & 15)) * 32 + (lane >> 4) * 8);

    #pragma unroll
    for (int i = 0; i < 2; ++i)
      #pragma unroll
      for (int j = 0; j < 2; ++j)
        acc[i][j] = __builtin_amdgcn_mfma_f32_16x16x32_bf16(af[i], bfr[j], acc[i][j], 0, 0, 0);
  }

  // epilogue: D mapping col=lane&15, row=(lane>>4)*4+reg
  float bvals[2];
  #pragma unroll
  for (int j = 0; j < 2; ++j) bvals[j] = bias[n0 + wn + j * 16 + (lane & 15)];
  const int r0 = (lane >> 4) * 4;
  #pragma unroll
  for (int i = 0; i < 2; ++i) {
    #pragma unroll
    for (int r = 0; r < 4; ++r) {
      const int gm = m0 + i * 16 + r0 + r;
      float* orow = out + (size_t)gm * 768 + n0 + wn;
      #pragma unroll
      for (int j = 0; j < 2; ++j)
        orow[j * 16 + (lane & 15)] = acc[i][j][r] + bvals[j];
    }
  }
}

extern "C" void kernel_launch(void* const* d_in, const int* in_sizes, int n_in,
                              void* d_out, int out_size, void* d_ws, size_t ws_size,
                              hipStream_t stream) {
  const int* token_ids       = (const int*)d_in[0];
  const int* segment_ids     = (const int*)d_in[1];
  const int* section_ids     = (const int*)d_in[2];
  const int* temporality_ids = (const int*)d_in[3];
  const int* negation_ids    = (const int*)d_in[4];
  const int* position_ids    = (const int*)d_in[5];
  const int* timestamp_ids   = (const int*)d_in[6];
  const float* token_table       = (const float*)d_in[7];
  const float* section_table     = (const float*)d_in[8];
  const float* temporality_table = (const float*)d_in[9];
  const float* negation_table    = (const float*)d_in[10];
  const float* position_table    = (const float*)d_in[11];
  const float* timestamp_table   = (const float*)d_in[12];
  const float* ln_gamma = (const float*)d_in[13];
  const float* ln_beta  = (const float*)d_in[14];
  const float* proj_w   = (const float*)d_in[15];
  const float* proj_b   = (const float*)d_in[16];

  float* out = (float*)d_out;
  bf16* wsW = (bf16*)d_ws;                        // 768*768 bf16   (1.18 MB)
  bf16* wsN = wsW + (size_t)Dn * Dn;              // 4096*768 bf16  (6.29 MB)
  int*  wsS = (int*)((char*)d_ws + (size_t)(Dn * Dn + NSEG * Dn) * 2);  // 4097 ints

  // W->bf16 (576) + mask zeros (16) + segment bounds (256)
  k_prep<<<848, 256, 0, stream>>>(proj_w, wsW, out + (size_t)NSEG * Dn,
                                  segment_ids, wsS);
  // pool + enrich + LN -> bf16 normed (one wave per segment)
  k_pool_ln<<<NSEG, 64, 0, stream>>>(token_ids, wsS, section_ids,
      temporality_ids, negation_ids, position_ids, timestamp_ids,
      token_table, section_table, temporality_table, negation_table,
      position_table, timestamp_table, ln_gamma, ln_beta, wsN);
  // projection GEMM + bias (768 blocks, 3/CU)
  k_gemm<<<dim3(6, 128), 256, 0, stream>>>(wsN, wsW, proj_b, out);
}